// Round 3
// baseline (458.194 us; speedup 1.0000x reference)
//
#include <hip/hip_runtime.h>

// MPOLinear3: out[B,x,y,z] = sum_{a,b,c} x[B,a,b,c]*F[a,x]*M2[b,y]*L[c,z] + bias
// where F = sum_j first[a,j,x], M2 = sum_{r1,r2} middle[b,r1,r2,y], L = sum_j last[c,j,z].
// (Reference einsums sum rank axes independently -> pure Kronecker of 3 16x16 mats.)
//
// R3: same as R2 (persistent blocks + register prefetch + nontemporal streams)
// but with clang ext_vector_type for the nontemporal builtins (HIP_vector_type
// is a struct and is rejected by __builtin_nontemporal_*).

#define LEG 16

typedef float f4 __attribute__((ext_vector_type(4)));

// Prep: reduce cores into W (d_ws): WF[x*16+a]=F[a,x], WM[y*16+b]=M2[b,y], WL[z*16+c]=L[c,z]
__global__ __launch_bounds__(256) void mpo_prep(
    const float* __restrict__ first, const float* __restrict__ middle,
    const float* __restrict__ last, float* __restrict__ W)
{
    __shared__ float red[256];
    const int t = threadIdx.x;
    const int blk = blockIdx.x;
    if (blk == 0) {
        const int xo = t >> 4, a = t & 15;
        float s = 0.f;
        #pragma unroll 8
        for (int j = 0; j < 64; ++j) s += first[a * 1024 + j * 16 + xo];
        W[t] = s;                       // WF[xo*16 + a]
    } else if (blk == 1) {
        const int z = t >> 4, c = t & 15;
        float s = 0.f;
        #pragma unroll 8
        for (int j = 0; j < 64; ++j) s += last[c * 1024 + j * 16 + z];
        W[512 + t] = s;                 // WL[z*16 + c]
    } else {
        const int b = blk - 2;          // 0..15
        const int g = t >> 4, y = t & 15;
        float s = 0.f;
        for (int r1 = g; r1 < 64; r1 += 16) {
            const float* p = middle + (size_t)b * 65536 + (size_t)r1 * 1024 + y;
            #pragma unroll 8
            for (int r2 = 0; r2 < 64; ++r2) s += p[r2 * 16];
        }
        red[t] = s;
        __syncthreads();
        if (t < 16) {
            float tot = 0.f;
            #pragma unroll
            for (int g2 = 0; g2 < 16; ++g2) tot += red[g2 * 16 + t];
            W[256 + t * 16 + b] = tot;  // WM[y*16 + b]
        }
    }
}

// Main: persistent blocks; each block processes rows row0, row0+grid, ...
// Per row: 3 mode products via LDS ping-pong; next row prefetched into regs.
__global__ __launch_bounds__(256, 4) void mpo_main(
    const float* __restrict__ x, const float* __restrict__ W,
    const float* __restrict__ bias, float* __restrict__ out, int nrows)
{
    __shared__ float bufA[4352];   // x row [a][b][c] flat; later stage-2 out, stride 17
    __shared__ float bufB[4224];   // stage-1 out [xo][b*16+c], stride 264

    const int t = threadIdx.x;

    // bias for this thread's 16 output columns, held in regs (cached, tiny)
    f4 bv[4];
    #pragma unroll
    for (int i = 0; i < 4; ++i)
        bv[i] = *(const f4*)(bias + t * 16 + i * 4);

    const float* WF = W;        // [x][a]
    const float* WM = W + 256;  // [y][b]
    const float* WL = W + 512;  // [z][c]

    // prologue: load first row into regs (nontemporal: pure stream)
    f4 xr[4];
    {
        const float* xrow = x + (size_t)blockIdx.x * 4096;
        #pragma unroll
        for (int i = 0; i < 4; ++i)
            xr[i] = __builtin_nontemporal_load((const f4*)(xrow + (i * 256 + t) * 4));
    }

    for (int row = blockIdx.x; row < nrows; row += gridDim.x) {
        // commit current row regs -> LDS
        #pragma unroll
        for (int i = 0; i < 4; ++i)
            *(f4*)(bufA + (i * 256 + t) * 4) = xr[i];
        __syncthreads();

        // prefetch next row into regs; latency hides under stages 1-3
        {
            const int nrow = row + (int)gridDim.x;
            if (nrow < nrows) {
                const float* nx = x + (size_t)nrow * 4096;
                #pragma unroll
                for (int i = 0; i < 4; ++i)
                    xr[i] = __builtin_nontemporal_load((const f4*)(nx + (i * 256 + t) * 4));
            }
        }

        // ---- Stage 1: t1[xo][b][c] = sum_a x[a][b][c]*F[a][xo]; thread owns (b,c)=t
        {
            float xa[16];
            #pragma unroll
            for (int a = 0; a < 16; ++a) xa[a] = bufA[a * 256 + t];
            #pragma unroll
            for (int q = 0; q < 4; ++q) {
                float acc[4] = {0.f, 0.f, 0.f, 0.f};
                #pragma unroll
                for (int a = 0; a < 16; ++a) {
                    #pragma unroll
                    for (int j = 0; j < 4; ++j)
                        acc[j] += xa[a] * WF[(q * 4 + j) * 16 + a];
                }
                #pragma unroll
                for (int j = 0; j < 4; ++j)
                    bufB[(q * 4 + j) * 264 + t] = acc[j];
            }
        }
        __syncthreads();

        // ---- Stage 2: t2[xo][y][c] = sum_b t1[xo][b][c]*M2[b][y]; thread owns (xo,c)
        {
            const int x_ = t >> 4, c_ = t & 15;
            float tb[16];
            #pragma unroll
            for (int b = 0; b < 16; ++b) tb[b] = bufB[x_ * 264 + b * 16 + c_];
            #pragma unroll
            for (int q = 0; q < 4; ++q) {
                float acc[4] = {0.f, 0.f, 0.f, 0.f};
                #pragma unroll
                for (int b = 0; b < 16; ++b) {
                    #pragma unroll
                    for (int j = 0; j < 4; ++j)
                        acc[j] += tb[b] * WM[(q * 4 + j) * 16 + b];
                }
                #pragma unroll
                for (int j = 0; j < 4; ++j)
                    bufA[(x_ * 16 + q * 4 + j) * 17 + c_] = acc[j];   // [p=(xo,y)] stride 17
            }
        }
        __syncthreads();

        // ---- Stage 3: out[xo][y][z] = sum_c t2[xo][y][c]*L[c][z] + bias; thread owns p=t
        float tc[16];
        #pragma unroll
        for (int c = 0; c < 16; ++c) tc[c] = bufA[t * 17 + c];
        __syncthreads();   // after this, all LDS reads done -> next iter may overwrite bufA

        {
            float* orow = out + (size_t)row * 4096;
            #pragma unroll
            for (int q = 0; q < 4; ++q) {
                float acc[4] = {bv[q].x, bv[q].y, bv[q].z, bv[q].w};
                #pragma unroll
                for (int c = 0; c < 16; ++c) {
                    #pragma unroll
                    for (int j = 0; j < 4; ++j)
                        acc[j] += tc[c] * WL[(q * 4 + j) * 16 + c];
                }
                f4 o;
                o.x = acc[0]; o.y = acc[1]; o.z = acc[2]; o.w = acc[3];
                __builtin_nontemporal_store(o, (f4*)(orow + t * 16 + q * 4));
            }
        }
    }
}

extern "C" void kernel_launch(void* const* d_in, const int* in_sizes, int n_in,
                              void* d_out, int out_size, void* d_ws, size_t ws_size,
                              hipStream_t stream) {
    const float* x      = (const float*)d_in[0];
    const float* first  = (const float*)d_in[1];
    const float* middle = (const float*)d_in[2];
    const float* last   = (const float*)d_in[3];
    const float* bias   = (const float*)d_in[4];
    float* out = (float*)d_out;
    float* W   = (float*)d_ws;          // 768 floats: WF | WM | WL

    const int Brows = in_sizes[0] / 4096;
    int grid = 1024;                    // 4 blocks/CU x 256 CU, persistent
    if (grid > Brows) grid = Brows;

    hipLaunchKernelGGL(mpo_prep, dim3(18), dim3(256), 0, stream,
                       first, middle, last, W);
    hipLaunchKernelGGL(mpo_main, dim3(grid), dim3(256), 0, stream,
                       x, W, bias, out, Brows);
}

// Round 5
// 211.975 us; speedup vs baseline: 2.1615x; 2.1615x over previous
//
#include <hip/hip_runtime.h>

// MPOLinear3: out[B,x,y,z] = sum_{a,b,c} x[B,a,b,c]*F[a,x]*M2[b,y]*L[c,z] + bias
// where F = sum_j first[a,j,x], M2 = sum_{r1,r2} middle[b,r1,r2,y], L = sum_j last[c,j,z].
// (Reference einsums sum rank axes independently -> pure Kronecker of 3 16x16 mats.)
//
// R5: exactly R3's validated structure (persistent blocks + register prefetch,
// 4 barriers/row) with the ONE proven poison removed: no nontemporal builtins.
// R3's NT stores caused 2.8x write amplification (708MB vs 256MB ideal) because
// strided 16B/64B-line stores bypassed L2 write merging. Cached stores from the
// same wave should merge to full lines. R4's zbuf copy-out variant failed
// validation non-deterministically; shelved until counters prove it's needed.

#define LEG 16

typedef float f4 __attribute__((ext_vector_type(4)));

// Prep: reduce cores into W (d_ws): WF[x*16+a]=F[a,x], WM[y*16+b]=M2[b,y], WL[z*16+c]=L[c,z]
__global__ __launch_bounds__(256) void mpo_prep(
    const float* __restrict__ first, const float* __restrict__ middle,
    const float* __restrict__ last, float* __restrict__ W)
{
    __shared__ float red[256];
    const int t = threadIdx.x;
    const int blk = blockIdx.x;
    if (blk == 0) {
        const int xo = t >> 4, a = t & 15;
        float s = 0.f;
        #pragma unroll 8
        for (int j = 0; j < 64; ++j) s += first[a * 1024 + j * 16 + xo];
        W[t] = s;                       // WF[xo*16 + a]
    } else if (blk == 1) {
        const int z = t >> 4, c = t & 15;
        float s = 0.f;
        #pragma unroll 8
        for (int j = 0; j < 64; ++j) s += last[c * 1024 + j * 16 + z];
        W[512 + t] = s;                 // WL[z*16 + c]
    } else {
        const int b = blk - 2;          // 0..15
        const int g = t >> 4, y = t & 15;
        float s = 0.f;
        for (int r1 = g; r1 < 64; r1 += 16) {
            const float* p = middle + (size_t)b * 65536 + (size_t)r1 * 1024 + y;
            #pragma unroll 8
            for (int r2 = 0; r2 < 64; ++r2) s += p[r2 * 16];
        }
        red[t] = s;
        __syncthreads();
        if (t < 16) {
            float tot = 0.f;
            #pragma unroll
            for (int g2 = 0; g2 < 16; ++g2) tot += red[g2 * 16 + t];
            W[256 + t * 16 + b] = tot;  // WM[y*16 + b]
        }
    }
}

// Main: persistent blocks; each block processes rows row0, row0+grid, ...
// Per row: 3 mode products via LDS ping-pong; next row prefetched into regs.
__global__ __launch_bounds__(256, 4) void mpo_main(
    const float* __restrict__ x, const float* __restrict__ W,
    const float* __restrict__ bias, float* __restrict__ out, int nrows)
{
    __shared__ float bufA[4352];   // x row [a][b][c] flat; later stage-2 out, stride 17
    __shared__ float bufB[4224];   // stage-1 out [xo][b*16+c], stride 264

    const int t = threadIdx.x;

    // bias for this thread's 16 output columns, held in regs (cached, tiny)
    f4 bv[4];
    #pragma unroll
    for (int i = 0; i < 4; ++i)
        bv[i] = *(const f4*)(bias + t * 16 + i * 4);

    const float* WF = W;        // [x][a]
    const float* WM = W + 256;  // [y][b]
    const float* WL = W + 512;  // [z][c]

    // prologue: load first row into regs
    f4 xr[4];
    {
        const float* xrow = x + (size_t)blockIdx.x * 4096;
        #pragma unroll
        for (int i = 0; i < 4; ++i)
            xr[i] = *(const f4*)(xrow + (i * 256 + t) * 4);
    }

    for (int row = blockIdx.x; row < nrows; row += gridDim.x) {
        // commit current row regs -> LDS
        #pragma unroll
        for (int i = 0; i < 4; ++i)
            *(f4*)(bufA + (i * 256 + t) * 4) = xr[i];
        __syncthreads();

        // prefetch next row into regs; latency hides under stages 1-3
        {
            const int nrow = row + (int)gridDim.x;
            if (nrow < nrows) {
                const float* nx = x + (size_t)nrow * 4096;
                #pragma unroll
                for (int i = 0; i < 4; ++i)
                    xr[i] = *(const f4*)(nx + (i * 256 + t) * 4);
            }
        }

        // ---- Stage 1: t1[xo][b][c] = sum_a x[a][b][c]*F[a][xo]; thread owns (b,c)=t
        {
            float xa[16];
            #pragma unroll
            for (int a = 0; a < 16; ++a) xa[a] = bufA[a * 256 + t];
            #pragma unroll
            for (int q = 0; q < 4; ++q) {
                float acc[4] = {0.f, 0.f, 0.f, 0.f};
                #pragma unroll
                for (int a = 0; a < 16; ++a) {
                    #pragma unroll
                    for (int j = 0; j < 4; ++j)
                        acc[j] += xa[a] * WF[(q * 4 + j) * 16 + a];
                }
                #pragma unroll
                for (int j = 0; j < 4; ++j)
                    bufB[(q * 4 + j) * 264 + t] = acc[j];
            }
        }
        __syncthreads();

        // ---- Stage 2: t2[xo][y][c] = sum_b t1[xo][b][c]*M2[b][y]; thread owns (xo,c)
        {
            const int x_ = t >> 4, c_ = t & 15;
            float tb[16];
            #pragma unroll
            for (int b = 0; b < 16; ++b) tb[b] = bufB[x_ * 264 + b * 16 + c_];
            #pragma unroll
            for (int q = 0; q < 4; ++q) {
                float acc[4] = {0.f, 0.f, 0.f, 0.f};
                #pragma unroll
                for (int b = 0; b < 16; ++b) {
                    #pragma unroll
                    for (int j = 0; j < 4; ++j)
                        acc[j] += tb[b] * WM[(q * 4 + j) * 16 + b];
                }
                #pragma unroll
                for (int j = 0; j < 4; ++j)
                    bufA[(x_ * 16 + q * 4 + j) * 17 + c_] = acc[j];   // [p=(xo,y)] stride 17
            }
        }
        __syncthreads();

        // ---- Stage 3: out[xo][y][z] = sum_c t2[xo][y][c]*L[c][z] + bias; thread owns p=t
        float tc[16];
        #pragma unroll
        for (int c = 0; c < 16; ++c) tc[c] = bufA[t * 17 + c];
        __syncthreads();   // after this, all LDS reads done -> next iter may overwrite bufA

        {
            float* orow = out + (size_t)row * 4096;
            #pragma unroll
            for (int q = 0; q < 4; ++q) {
                float acc[4] = {bv[q].x, bv[q].y, bv[q].z, bv[q].w};
                #pragma unroll
                for (int c = 0; c < 16; ++c) {
                    #pragma unroll
                    for (int j = 0; j < 4; ++j)
                        acc[j] += tc[c] * WL[(q * 4 + j) * 16 + c];
                }
                f4 o;
                o.x = acc[0]; o.y = acc[1]; o.z = acc[2]; o.w = acc[3];
                *(f4*)(orow + t * 16 + q * 4) = o;
            }
        }
    }
}

extern "C" void kernel_launch(void* const* d_in, const int* in_sizes, int n_in,
                              void* d_out, int out_size, void* d_ws, size_t ws_size,
                              hipStream_t stream) {
    const float* x      = (const float*)d_in[0];
    const float* first  = (const float*)d_in[1];
    const float* middle = (const float*)d_in[2];
    const float* last   = (const float*)d_in[3];
    const float* bias   = (const float*)d_in[4];
    float* out = (float*)d_out;
    float* W   = (float*)d_ws;          // 768 floats: WF | WM | WL

    const int Brows = in_sizes[0] / 4096;
    int grid = 1024;                    // 4 blocks/CU x 256 CU, persistent
    if (grid > Brows) grid = Brows;

    hipLaunchKernelGGL(mpo_prep, dim3(18), dim3(256), 0, stream,
                       first, middle, last, W);
    hipLaunchKernelGGL(mpo_main, dim3(grid), dim3(256), 0, stream,
                       x, W, bias, out, Brows);
}

// Round 6
// 152.873 us; speedup vs baseline: 2.9972x; 1.3866x over previous
//
#include <hip/hip_runtime.h>

// MPOLinear3: out[B,x,y,z] = sum_{a,b,c} x[B,a,b,c]*F[a,x]*M2[b,y]*L[c,z] + bias
// where F = sum_j first[a,j,x], M2 = sum_{r1,r2} middle[b,r1,r2,y], L = sum_j last[c,j,z].
// (Reference einsums sum rank axes independently -> pure Kronecker of 3 16x16 mats.)
//
// R6: back to R1's proven-fastest config (one block per row, 16384 blocks,
// block churn = natural pipelining; persistence in R5 was 40% slower at 25%
// HBM / 75% VALUBusy). One change: x staged via global_load_lds width=16
// (drops the VGPR round-trip: 4 global loads + 4 ds_write_b128 + 16 regs).
// Cached stores proven to merge (R5: WRITE 270MB ~= ideal).

#define LEG 16

typedef float f4 __attribute__((ext_vector_type(4)));

// Prep: reduce cores into W (d_ws): WF[x*16+a]=F[a,x], WM[y*16+b]=M2[b,y], WL[z*16+c]=L[c,z]
__global__ __launch_bounds__(256) void mpo_prep(
    const float* __restrict__ first, const float* __restrict__ middle,
    const float* __restrict__ last, float* __restrict__ W)
{
    __shared__ float red[256];
    const int t = threadIdx.x;
    const int blk = blockIdx.x;
    if (blk == 0) {
        const int xo = t >> 4, a = t & 15;
        float s = 0.f;
        #pragma unroll 8
        for (int j = 0; j < 64; ++j) s += first[a * 1024 + j * 16 + xo];
        W[t] = s;                       // WF[xo*16 + a]
    } else if (blk == 1) {
        const int z = t >> 4, c = t & 15;
        float s = 0.f;
        #pragma unroll 8
        for (int j = 0; j < 64; ++j) s += last[c * 1024 + j * 16 + z];
        W[512 + t] = s;                 // WL[z*16 + c]
    } else {
        const int b = blk - 2;          // 0..15
        const int g = t >> 4, y = t & 15;
        float s = 0.f;
        for (int r1 = g; r1 < 64; r1 += 16) {
            const float* p = middle + (size_t)b * 65536 + (size_t)r1 * 1024 + y;
            #pragma unroll 8
            for (int r2 = 0; r2 < 64; ++r2) s += p[r2 * 16];
        }
        red[t] = s;
        __syncthreads();
        if (t < 16) {
            float tot = 0.f;
            #pragma unroll
            for (int g2 = 0; g2 < 16; ++g2) tot += red[g2 * 16 + t];
            W[256 + t * 16 + b] = tot;  // WM[y*16 + b]
        }
    }
}

// Main: one block per batch row; 3 LDS mode products, 3 barriers; block exits.
__global__ __launch_bounds__(256, 4) void mpo_main(
    const float* __restrict__ x, const float* __restrict__ W,
    const float* __restrict__ bias, float* __restrict__ out)
{
    __shared__ float bufA[4352];   // x row flat [a*256+bc]; later t2 [p*17+c]
    __shared__ float bufB[4224];   // t1 [xo*264+b*16+c]

    const int t = threadIdx.x;
    const int w = t >> 6;          // wave id (0..3)
    const int l = t & 63;          // lane
    const float* xrow = x + (size_t)blockIdx.x * 4096;

    // async global->LDS staging: chunk i, wave w -> bufA floats [i*1024+w*256 ..+255]
    // HW semantics: wave-uniform LDS base + lane*16B; matches gsrc per-lane.
    #pragma unroll
    for (int i = 0; i < 4; ++i) {
        const float* g = xrow + i * 1024 + w * 256 + l * 4;
        float* lp = &bufA[i * 1024 + w * 256];
        __builtin_amdgcn_global_load_lds(
            (const __attribute__((address_space(1))) uint32_t*)(const void*)g,
            (__attribute__((address_space(3))) uint32_t*)(void*)lp,
            16, 0, 0);
    }

    // bias for this thread's 16 output columns (loads overlap the staging)
    f4 bv[4];
    #pragma unroll
    for (int i = 0; i < 4; ++i)
        bv[i] = *(const f4*)(bias + t * 16 + i * 4);

    const float* WF = W;        // [x][a]
    const float* WM = W + 256;  // [y][b]
    const float* WL = W + 512;  // [z][c]

    __syncthreads();   // drains vmcnt incl. global_load_lds

    // ---- Stage 1: t1[xo][b][c] = sum_a x[a][b][c]*F[a][xo]; thread owns (b,c)=t
    {
        float xa[16];
        #pragma unroll
        for (int a = 0; a < 16; ++a) xa[a] = bufA[a * 256 + t];
        #pragma unroll
        for (int q = 0; q < 4; ++q) {
            float acc[4] = {0.f, 0.f, 0.f, 0.f};
            #pragma unroll
            for (int a = 0; a < 16; ++a) {
                #pragma unroll
                for (int j = 0; j < 4; ++j)
                    acc[j] += xa[a] * WF[(q * 4 + j) * 16 + a];
            }
            #pragma unroll
            for (int j = 0; j < 4; ++j)
                bufB[(q * 4 + j) * 264 + t] = acc[j];
        }
    }
    __syncthreads();

    // ---- Stage 2: t2[xo][y][c] = sum_b t1[xo][b][c]*M2[b][y]; thread owns (xo,c)
    {
        const int x_ = t >> 4, c_ = t & 15;
        float tb[16];
        #pragma unroll
        for (int b = 0; b < 16; ++b) tb[b] = bufB[x_ * 264 + b * 16 + c_];
        #pragma unroll
        for (int q = 0; q < 4; ++q) {
            float acc[4] = {0.f, 0.f, 0.f, 0.f};
            #pragma unroll
            for (int b = 0; b < 16; ++b) {
                #pragma unroll
                for (int j = 0; j < 4; ++j)
                    acc[j] += tb[b] * WM[(q * 4 + j) * 16 + b];
            }
            #pragma unroll
            for (int j = 0; j < 4; ++j)
                bufA[(x_ * 16 + q * 4 + j) * 17 + c_] = acc[j];   // t2[p*17+c]
        }
    }
    __syncthreads();

    // ---- Stage 3: out[p][z] = sum_c t2[p][c]*L[c][z] + bias; thread owns p=(xo,y)=t
    {
        float tc[16];
        #pragma unroll
        for (int c = 0; c < 16; ++c) tc[c] = bufA[t * 17 + c];

        float* orow = out + (size_t)blockIdx.x * 4096;
        #pragma unroll
        for (int q = 0; q < 4; ++q) {
            float acc[4] = {bv[q].x, bv[q].y, bv[q].z, bv[q].w};
            #pragma unroll
            for (int c = 0; c < 16; ++c) {
                #pragma unroll
                for (int j = 0; j < 4; ++j)
                    acc[j] += tc[c] * WL[(q * 4 + j) * 16 + c];
            }
            f4 o;
            o.x = acc[0]; o.y = acc[1]; o.z = acc[2]; o.w = acc[3];
            *(f4*)(orow + t * 16 + q * 4) = o;
        }
    }
}

extern "C" void kernel_launch(void* const* d_in, const int* in_sizes, int n_in,
                              void* d_out, int out_size, void* d_ws, size_t ws_size,
                              hipStream_t stream) {
    const float* x      = (const float*)d_in[0];
    const float* first  = (const float*)d_in[1];
    const float* middle = (const float*)d_in[2];
    const float* last   = (const float*)d_in[3];
    const float* bias   = (const float*)d_in[4];
    float* out = (float*)d_out;
    float* W   = (float*)d_ws;          // 768 floats: WF | WM | WL

    const int Brows = in_sizes[0] / 4096;

    hipLaunchKernelGGL(mpo_prep, dim3(18), dim3(256), 0, stream,
                       first, middle, last, W);
    hipLaunchKernelGGL(mpo_main, dim3(Brows), dim3(256), 0, stream,
                       x, W, bias, out);
}